// Round 5
// baseline (1785.686 us; speedup 1.0000x reference)
//
#include <hip/hip_runtime.h>
#include <cstdint>
#include <cstddef>

#define NN  768
#define IND 64
#define HD  128
#define EFD 16
#define TT  3
#define NC  16      // i-chunks in msgmax
#define CHUNK 48    // 768/NC
#define GRID 512
#define NTHR 256

typedef __attribute__((ext_vector_type(8)))  short short8;
typedef __attribute__((ext_vector_type(16))) float floatx16;

__device__ __forceinline__ unsigned short f2bf(float f){
    unsigned u = __float_as_uint(f);
    unsigned r = (u + 0x7FFFu + ((u >> 16) & 1u)) >> 16;
    return (unsigned short)r;
}

// grid-wide barrier (mirrors __ockl_grid_sync): requires all GRID blocks co-resident.
// __launch_bounds__(256,2) -> 2 blocks/CU guaranteed -> 512 blocks on 256 CUs.
__device__ __forceinline__ void gbar(unsigned* ctr, unsigned target){
    __threadfence();          // agent-scope release by every thread
    __syncthreads();
    if (threadIdx.x == 0){
        atomicAdd(ctr, 1u);   // device-scope by default
        while (__hip_atomic_load(ctr, __ATOMIC_RELAXED, __HIP_MEMORY_SCOPE_AGENT) < target)
            __builtin_amdgcn_s_sleep(1);
    }
    __syncthreads();
    __threadfence();          // agent-scope acquire
}

__global__ void zero_ker(unsigned* ctr){
    if (threadIdx.x == 0) *ctr = 0u;
}

__global__ __launch_bounds__(NTHR, 2)
void mega_ker(const float* __restrict__ states, const float* __restrict__ edges,
              const float* __restrict__ We, const float* __restrict__ be,
              const float* __restrict__ Wm, const float* __restrict__ bm,
              const float* __restrict__ Wu, const float* __restrict__ bu,
              const float* __restrict__ Wd, const float* __restrict__ bd,
              const float* __restrict__ Wt, const float* __restrict__ bt,
              float* __restrict__ out,
              float* __restrict__ z, float* __restrict__ zsrc, float* __restrict__ zdst,
              float* __restrict__ hid, float* __restrict__ state,
              unsigned long long* __restrict__ msbuf, unsigned* __restrict__ ctr,
              float* __restrict__ partial, unsigned short* __restrict__ ebf)
{
    const int bid = blockIdx.x, tid = threadIdx.x;
    const int gidbase = bid * NTHR + tid;
    unsigned tgt = 0;

    __shared__ float sz[2][HD];
    __shared__ float sA[4][256];
    __shared__ float sH[4][HD];

    // ---------- phase 0: edges f32->bf16 + output init ----------
    {
        const float4* ef4 = reinterpret_cast<const float4*>(edges);
        uint2* eb2 = reinterpret_cast<uint2*>(ebf);
        for (int it = 0; it < 18; ++it){
            int gid = gidbase + it * (GRID * NTHR);   // 18*131072 = 2359296 float4
            float4 v = ef4[gid];
            uint2 p;
            p.x = (unsigned)f2bf(v.x) | ((unsigned)f2bf(v.y) << 16);
            p.y = (unsigned)f2bf(v.z) | ((unsigned)f2bf(v.w) << 16);
            eb2[gid] = p;
        }
        if (gidbase < NN * IND){
            int n = gidbase >> 6, c = gidbase & 63;
            out[n * 256 + c] = states[n * IND + c];       // preds[n][0][c]
        }
        if (gidbase < NN * 2){
            int n = gidbase >> 1, cc = gidbase & 1;
            out[196608 + n * 8 + cc] = 0.f;               // preds_stop[n][0][cc]
        }
    }
    tgt += GRID; gbar(ctr, tgt);

    for (int t = 0; t < TT; ++t){
        const float* st = (t == 0) ? states : state;

        // ---------- phase 1: z + zsrc/zdst (blocks 0..383); ms zero + stop(t-1) (blocks 384..511) ----------
        if (bid < 384){
            int m0 = bid * 2;
            int n = tid & 127, mh = tid >> 7;
            int m = m0 + mh;
            float acc = be[n];
            const float* srow = st + m * IND;
            #pragma unroll
            for (int k = 0; k < IND; ++k) acc += srow[k] * We[k * HD + n];
            if (t > 0){
                const float* hrow = hid + m * HD;
                #pragma unroll
                for (int k = 0; k < HD; ++k) acc += hrow[k] * We[(IND + k) * HD + n];
            }
            z[m * HD + n] = acc;
            sz[mh][n] = acc;
            __syncthreads();
            float accS = 0.f, accD = 0.f;
            #pragma unroll 8
            for (int k = 0; k < HD; ++k){
                float v = sz[mh][k];
                accS += v * Wm[k * HD + n];
                accD += v * Wm[(HD + k) * HD + n];
            }
            zsrc[m * HD + n] = accS;
            zdst[m * HD + n] = accD;
        } else {
            int b2 = bid - 384;
            if (b2 == 0 && tid < HD) msbuf[(t & 1) * HD + tid] = 0ull;
            if (t > 0 && tid < 12){
                int row = b2 * 6 + (tid >> 1), cc = tid & 1;
                float a2 = bt[cc];
                const float* hrow = hid + row * HD;
                #pragma unroll 8
                for (int k = 0; k < HD; ++k) a2 += hrow[k] * Wt[k * 2 + cc];
                const unsigned long long* msp = msbuf + ((t - 1) & 1) * HD;
                const float sc = 1.0f / (768.0f * 1048576.0f);
                #pragma unroll 8
                for (int k = 0; k < HD; ++k){
                    float mk = (float)(long long)msp[k] * sc;
                    a2 += mk * Wt[(HD + k) * 2 + cc];
                }
                out[196608 + row * 8 + t * 2 + cc] = 1.f / (1.f + expf(-a2));
            }
        }
        tgt += GRID; gbar(ctr, tgt);

        // ---------- phase 2: MFMA msgmax -> partial[c][j][h] ----------
        if (bid < 384){
            const float* WmE = Wm + 2 * HD * HD;
            int lane = tid & 63;
            int wv = tid >> 6;
            int jt = bid % 24, ch = bid / 24;
            int j0 = jt * 32, h0 = wv * 32, i0 = ch * CHUNK;
            int ln = lane & 31, lh = lane >> 5;

            short8 b;
            #pragma unroll
            for (int q = 0; q < 8; ++q)
                b[q] = (short)f2bf(WmE[(8 * lh + q) * HD + h0 + ln]);

            floatx16 czero, run;
            #pragma unroll
            for (int r = 0; r < 16; ++r){ czero[r] = 0.f; run[r] = -INFINITY; }

            const unsigned short* abase = ebf + (size_t)(j0 + ln) * EFD + 8 * lh;
            #pragma unroll 2
            for (int ii = 0; ii < CHUNK; ++ii){
                int i = i0 + ii;
                short8 a = *reinterpret_cast<const short8*>(abase + (size_t)i * NN * EFD);
                float zsv = zsrc[i * HD + h0 + ln];
                floatx16 d = __builtin_amdgcn_mfma_f32_32x32x16_bf16(a, b, czero, 0, 0, 0);
                #pragma unroll
                for (int r = 0; r < 16; ++r) run[r] = fmaxf(run[r], d[r] + zsv);
            }
            float* pb = partial + ((size_t)ch * NN + j0) * HD + h0 + ln;
            #pragma unroll
            for (int r = 0; r < 16; ++r){
                int row = (r & 3) + 8 * (r >> 2) + 4 * lh;
                pb[(size_t)row * HD] = run[r];
            }
        }
        tgt += GRID; gbar(ctr, tgt);

        // ---------- phase 3: h_new + meansum + new_state + preds (blocks 0..191) ----------
        if (bid < 192){
            int m0 = bid * 4;
            #pragma unroll
            for (int r = 0; r < 4; ++r){
                int idx = tid + r * 256;
                int mm = idx >> 8, k = idx & 255;
                float v;
                if (k < HD) v = z[(m0 + mm) * HD + k];
                else {
                    int kk = k - HD;
                    float mx = -INFINITY;
                    #pragma unroll
                    for (int c2 = 0; c2 < NC; ++c2)
                        mx = fmaxf(mx, partial[((size_t)c2 * NN + (m0 + mm)) * HD + kk]);
                    v = mx + zdst[(m0 + mm) * HD + kk] + bm[kk];
                }
                sA[mm][k] = v;
            }
            __syncthreads();
            #pragma unroll
            for (int r = 0; r < 2; ++r){
                int idx = tid + r * 256;
                int mm = idx >> 7, h = idx & 127;
                float acc = bu[h];
                #pragma unroll 8
                for (int k = 0; k < 256; ++k) acc += sA[mm][k] * Wu[k * HD + h];
                hid[(m0 + mm) * HD + h] = acc;
                sH[mm][h] = acc;
            }
            __syncthreads();
            if (tid < HD){
                long long s = llrintf(sH[0][tid] * 1048576.f) + llrintf(sH[1][tid] * 1048576.f)
                            + llrintf(sH[2][tid] * 1048576.f) + llrintf(sH[3][tid] * 1048576.f);
                atomicAdd(&msbuf[(t & 1) * HD + tid], (unsigned long long)s);
            }
            {
                int c = tid & 63, mm = tid >> 6;
                float a = bd[c];
                #pragma unroll 8
                for (int k = 0; k < HD; ++k) a += sH[mm][k] * Wd[k * IND + c];
                #pragma unroll 8
                for (int k = 0; k < HD; ++k) a += sA[mm][k] * Wd[(HD + k) * IND + c];
                int m = m0 + mm;
                state[m * IND + c] = a;
                out[m * 256 + (t + 1) * IND + c] = a;
            }
        }
        tgt += GRID; gbar(ctr, tgt);
    }

    // ---------- final stop (step TT-1) ----------
    if (bid >= 384){
        int b2 = bid - 384;
        if (tid < 12){
            int row = b2 * 6 + (tid >> 1), cc = tid & 1;
            float a2 = bt[cc];
            const float* hrow = hid + row * HD;
            #pragma unroll 8
            for (int k = 0; k < HD; ++k) a2 += hrow[k] * Wt[k * 2 + cc];
            const unsigned long long* msp = msbuf + ((TT - 1) & 1) * HD;
            const float sc = 1.0f / (768.0f * 1048576.0f);
            #pragma unroll 8
            for (int k = 0; k < HD; ++k){
                float mk = (float)(long long)msp[k] * sc;
                a2 += mk * Wt[(HD + k) * 2 + cc];
            }
            out[196608 + row * 8 + TT * 2 + cc] = 1.f / (1.f + expf(-a2));
        }
    }
}

extern "C" void kernel_launch(void* const* d_in, const int* in_sizes, int n_in,
                              void* d_out, int out_size, void* d_ws, size_t ws_size,
                              hipStream_t stream){
    const float* states = (const float*)d_in[0];
    const float* edges  = (const float*)d_in[1];
    const float* We = (const float*)d_in[2];
    const float* be = (const float*)d_in[3];
    const float* Wm = (const float*)d_in[4];
    const float* bm = (const float*)d_in[5];
    const float* Wu = (const float*)d_in[6];
    const float* bu = (const float*)d_in[7];
    const float* Wd = (const float*)d_in[8];
    const float* bd = (const float*)d_in[9];
    const float* Wt = (const float*)d_in[10];
    const float* bt = (const float*)d_in[11];
    float* out = (float*)d_out;

    float* ws = (float*)d_ws;
    float* z       = ws;                        // 98304
    float* zsrc    = ws + 98304;                // 98304
    float* zdst    = ws + 196608;               // 98304
    float* hid     = ws + 294912;               // 98304
    float* state   = ws + 393216;               // 49152
    unsigned long long* msbuf = (unsigned long long*)(ws + 442368); // 256 ull = 512 floats
    unsigned* ctr  = (unsigned*)(ws + 442880);  // barrier counter (+pad to 443136)
    float* partial = ws + 443136;               // 16*768*128 = 1572864
    unsigned short* ebf = (unsigned short*)(ws + 2016000); // 9437184 bf16

    zero_ker<<<1, 64, 0, stream>>>(ctr);
    mega_ker<<<GRID, NTHR, 0, stream>>>(states, edges, We, be, Wm, bm, Wu, bu,
                                        Wd, bd, Wt, bt, out, z, zsrc, zdst, hid,
                                        state, msbuf, ctr, partial, ebf);
}

// Round 6
// 175.690 us; speedup vs baseline: 10.1639x; 10.1639x over previous
//
#include <hip/hip_runtime.h>
#include <cstdint>
#include <cstddef>

#define NN  768
#define IND 64
#define HD  128
#define EFD 16
#define TT  3
#define NC  16      // i-chunks in msgmax
#define CHUNK 48    // 768/NC

typedef __attribute__((ext_vector_type(8)))  short short8;
typedef __attribute__((ext_vector_type(16))) float floatx16;

__device__ __forceinline__ unsigned f2bf(float f){
    unsigned u = __float_as_uint(f);
    return (u + 0x7FFFu + ((u >> 16) & 1u)) >> 16;
}

// ---------- K1: z(0) + zsrc/zdst(0) row-local; edges f32->bf16; output init ----------
__global__ __launch_bounds__(256)
void k1_ker(const float* __restrict__ states, const float* __restrict__ edges,
            const float* __restrict__ We, const float* __restrict__ be,
            const float* __restrict__ Wm, float* __restrict__ out,
            float* __restrict__ z, float* __restrict__ zsrc, float* __restrict__ zdst,
            unsigned short* __restrict__ ebf)
{
    int bid = blockIdx.x, tid = threadIdx.x;
    __shared__ float sZ[HD];
    if (tid < HD){
        float acc = be[tid];
        const float* srow = states + bid * IND;
        #pragma unroll
        for (int k = 0; k < IND; ++k) acc += srow[k] * We[k * HD + tid];
        z[bid * HD + tid] = acc;
        sZ[tid] = acc;
    }
    __syncthreads();
    {
        int h = tid & 127, which = tid >> 7;
        const float* W = Wm + which * HD * HD;
        float acc = 0.f;
        #pragma unroll 8
        for (int k = 0; k < HD; ++k) acc += sZ[k] * W[k * HD + h];
        (which ? zdst : zsrc)[bid * HD + h] = acc;
    }
    // edges conv: 2359296 float4 over 768*256 threads = 12 iters
    const float4* ef4 = reinterpret_cast<const float4*>(edges);
    uint2* eb2 = reinterpret_cast<uint2*>(ebf);
    int gid0 = bid * 256 + tid;
    for (int it = 0; it < 12; ++it){
        int gid = gid0 + it * 196608;
        float4 v = ef4[gid];
        uint2 p;
        p.x = f2bf(v.x) | (f2bf(v.y) << 16);
        p.y = f2bf(v.z) | (f2bf(v.w) << 16);
        eb2[gid] = p;
    }
    if (gid0 < NN * IND){ int n = gid0 >> 6, c = gid0 & 63; out[n * 256 + c] = states[n * IND + c]; }
    if (gid0 < NN * 2){ int n = gid0 >> 1, cc = gid0 & 1; out[196608 + n * 8 + cc] = 0.f; }
}

// ---------- K2: MFMA msgmax (blocks 0..383) ; msbuf zero + deferred stop(t-1) (blocks 384..511) ----------
__global__ __launch_bounds__(256)
void k2_ker(const unsigned short* __restrict__ ebf, const float* __restrict__ zsrc,
            const float* __restrict__ Wm, float* __restrict__ partial,
            const float* __restrict__ hid, unsigned long long* __restrict__ msbuf,
            const float* __restrict__ Wt, const float* __restrict__ bt,
            float* __restrict__ out, int t)
{
    int bid = blockIdx.x, tid = threadIdx.x;
    if (bid < 384){
        const float* WmE = Wm + 2 * HD * HD;
        int lane = tid & 63;
        int wv = tid >> 6;
        int jt = bid % 24, ch = bid / 24;
        int j0 = jt * 32, h0 = wv * 32, i0 = ch * CHUNK;
        int ln = lane & 31, lh = lane >> 5;

        short8 b;
        #pragma unroll
        for (int q = 0; q < 8; ++q)
            b[q] = (short)f2bf(WmE[(8 * lh + q) * HD + h0 + ln]);

        floatx16 czero, run;
        #pragma unroll
        for (int r = 0; r < 16; ++r){ czero[r] = 0.f; run[r] = -INFINITY; }

        const unsigned short* abase = ebf + (size_t)(j0 + ln) * EFD + 8 * lh;
        #pragma unroll 2
        for (int ii = 0; ii < CHUNK; ++ii){
            int i = i0 + ii;
            short8 a = *reinterpret_cast<const short8*>(abase + (size_t)i * NN * EFD);
            float zsv = zsrc[i * HD + h0 + ln];
            floatx16 d = __builtin_amdgcn_mfma_f32_32x32x16_bf16(a, b, czero, 0, 0, 0);
            #pragma unroll
            for (int r = 0; r < 16; ++r) run[r] = fmaxf(run[r], d[r] + zsv);
        }
        float* pb = partial + ((size_t)ch * NN + j0) * HD + h0 + ln;
        #pragma unroll
        for (int r = 0; r < 16; ++r){
            int row = (r & 3) + 8 * (r >> 2) + 4 * lh;
            pb[(size_t)row * HD] = run[r];
        }
    } else {
        int b2 = bid - 384;
        if (b2 == 0 && tid < HD) msbuf[(t & 1) * HD + tid] = 0ull;
        if (t > 0 && tid < 12){
            int row = b2 * 6 + (tid >> 1), cc = tid & 1;
            float a2 = bt[cc];
            const float* hrow = hid + row * HD;
            #pragma unroll 8
            for (int k = 0; k < HD; ++k) a2 += hrow[k] * Wt[k * 2 + cc];
            const unsigned long long* msp = msbuf + ((t - 1) & 1) * HD;
            const float sc = 1.0f / (768.0f * 1048576.0f);
            #pragma unroll 8
            for (int k = 0; k < HD; ++k){
                float mk = (float)(long long)msp[k] * sc;
                a2 += mk * Wt[(HD + k) * 2 + cc];
            }
            out[196608 + row * 8 + t * 2 + cc] = 1.f / (1.f + expf(-a2));
        }
    }
}

// ---------- K3: hnew + meansum + new_state/preds + z(t+1) + zsrc/zdst(t+1), 2 rows/block ----------
__global__ __launch_bounds__(256)
void k3_ker(float* __restrict__ z, float* __restrict__ zsrc, float* __restrict__ zdst,
            const float* __restrict__ partial, const float* __restrict__ bm,
            const float* __restrict__ Wu, const float* __restrict__ bu,
            const float* __restrict__ Wd, const float* __restrict__ bd,
            const float* __restrict__ We, const float* __restrict__ be,
            const float* __restrict__ Wm,
            float* __restrict__ hid, float* __restrict__ state,
            unsigned long long* __restrict__ msbuf, float* __restrict__ out, int t)
{
    __shared__ float sA[2][256];   // [mm][k]: k<128 z, k>=128 u
    __shared__ float sH[2][HD];
    __shared__ float sS[2][IND];
    __shared__ float sZp[2][HD];
    int tid = threadIdx.x;
    int m0 = blockIdx.x * 2;

    #pragma unroll
    for (int r = 0; r < 2; ++r){
        int idx = tid + r * 256;
        int mm = idx >> 8, k = idx & 255;
        float v;
        if (k < HD) v = z[(m0 + mm) * HD + k];
        else {
            int kk = k - HD;
            float mx = -INFINITY;
            #pragma unroll
            for (int c2 = 0; c2 < NC; ++c2)
                mx = fmaxf(mx, partial[((size_t)c2 * NN + (m0 + mm)) * HD + kk]);
            v = mx + zdst[(m0 + mm) * HD + kk] + bm[kk];
        }
        sA[mm][k] = v;
    }
    __syncthreads();

    int mm = tid >> 7, h = tid & 127;
    {
        float acc = bu[h];
        #pragma unroll 8
        for (int k = 0; k < 256; ++k) acc += sA[mm][k] * Wu[k * HD + h];
        hid[(m0 + mm) * HD + h] = acc;
        sH[mm][h] = acc;
    }
    __syncthreads();

    if (tid < HD){
        long long s = llrintf(sH[0][tid] * 1048576.f) + llrintf(sH[1][tid] * 1048576.f);
        atomicAdd(&msbuf[(t & 1) * HD + tid], (unsigned long long)s);
    }
    if (tid < 128){
        int c = tid & 63, mm2 = tid >> 6;
        float a = bd[c];
        #pragma unroll 8
        for (int k = 0; k < HD; ++k) a += sH[mm2][k] * Wd[k * IND + c];
        #pragma unroll 8
        for (int k = 0; k < HD; ++k) a += sA[mm2][k] * Wd[(HD + k) * IND + c];
        state[(m0 + mm2) * IND + c] = a;
        out[(m0 + mm2) * 256 + (t + 1) * IND + c] = a;
        sS[mm2][c] = a;
    }
    __syncthreads();

    if (t < TT - 1){
        float acc2 = be[h];
        #pragma unroll
        for (int k = 0; k < IND; ++k) acc2 += sS[mm][k] * We[k * HD + h];
        #pragma unroll 8
        for (int k = 0; k < HD; ++k) acc2 += sH[mm][k] * We[(IND + k) * HD + h];
        z[(m0 + mm) * HD + h] = acc2;
        sZp[mm][h] = acc2;
        __syncthreads();

        float accS = 0.f, accD = 0.f;
        #pragma unroll 8
        for (int k = 0; k < HD; ++k){
            float v = sZp[mm][k];
            accS += v * Wm[k * HD + h];
            accD += v * Wm[(HD + k) * HD + h];
        }
        zsrc[(m0 + mm) * HD + h] = accS;
        zdst[(m0 + mm) * HD + h] = accD;
    }
}

// ---------- final stop (t = TT-1) ----------
__global__ void kstop_ker(const float* __restrict__ hid, const unsigned long long* __restrict__ msbuf,
                          const float* __restrict__ Wt, const float* __restrict__ bt,
                          float* __restrict__ out)
{
    int tid = threadIdx.x;
    if (tid < 12){
        int row = blockIdx.x * 6 + (tid >> 1), cc = tid & 1;
        float a2 = bt[cc];
        const float* hrow = hid + row * HD;
        #pragma unroll 8
        for (int k = 0; k < HD; ++k) a2 += hrow[k] * Wt[k * 2 + cc];
        const unsigned long long* msp = msbuf + ((TT - 1) & 1) * HD;
        const float sc = 1.0f / (768.0f * 1048576.0f);
        #pragma unroll 8
        for (int k = 0; k < HD; ++k){
            float mk = (float)(long long)msp[k] * sc;
            a2 += mk * Wt[(HD + k) * 2 + cc];
        }
        out[196608 + row * 8 + TT * 2 + cc] = 1.f / (1.f + expf(-a2));
    }
}

extern "C" void kernel_launch(void* const* d_in, const int* in_sizes, int n_in,
                              void* d_out, int out_size, void* d_ws, size_t ws_size,
                              hipStream_t stream){
    const float* states = (const float*)d_in[0];
    const float* edges  = (const float*)d_in[1];
    const float* We = (const float*)d_in[2];
    const float* be = (const float*)d_in[3];
    const float* Wm = (const float*)d_in[4];
    const float* bm = (const float*)d_in[5];
    const float* Wu = (const float*)d_in[6];
    const float* bu = (const float*)d_in[7];
    const float* Wd = (const float*)d_in[8];
    const float* bd = (const float*)d_in[9];
    const float* Wt = (const float*)d_in[10];
    const float* bt = (const float*)d_in[11];
    float* out = (float*)d_out;

    float* ws = (float*)d_ws;
    float* z       = ws;                        // 98304
    float* zsrc    = ws + 98304;                // 98304
    float* zdst    = ws + 196608;               // 98304
    float* hid     = ws + 294912;               // 98304
    float* state   = ws + 393216;               // 49152
    unsigned long long* msbuf = (unsigned long long*)(ws + 442368); // 256 ull
    float* partial = ws + 443136;               // 16*768*128 = 1572864
    unsigned short* ebf = (unsigned short*)(ws + 2016000); // 9437184 bf16

    k1_ker<<<768, 256, 0, stream>>>(states, edges, We, be, Wm, out, z, zsrc, zdst, ebf);
    for (int t = 0; t < TT; ++t){
        k2_ker<<<512, 256, 0, stream>>>(ebf, zsrc, Wm, partial, hid, msbuf, Wt, bt, out, t);
        k3_ker<<<384, 256, 0, stream>>>(z, zsrc, zdst, partial, bm, Wu, bu, Wd, bd,
                                        We, be, Wm, hid, state, msbuf, out, t);
    }
    kstop_ker<<<128, 256, 0, stream>>>(hid, msbuf, Wt, bt, out);
}